// Round 11
// baseline (1470.176 us; speedup 1.0000x reference)
//
#include <hip/hip_runtime.h>
#include <stdint.h>

typedef _Float16 f16;
typedef _Float16 f16x8 __attribute__((ext_vector_type(8)));
typedef float f32x4 __attribute__((ext_vector_type(4)));

#define INF_F __builtin_inff()
#define INF_I 0x7fffffff
#define KM 24            // merge candidate margin
#define SCALE 262144.0f  // 2^18 fixed-point scale

__device__ __forceinline__ bool lexLess(float s1, int n1, float s2, int n2) {
    return (s1 < s2) || (s1 == s2 && n1 < n2);
}
__device__ __forceinline__ bool lexLessI(int s1, int n1, int s2, int n2) {
    return (s1 < s2) || (s1 == s2 && n1 < n2);
}

__device__ __forceinline__ uint4 pack8(const float4 a, const float4 b) {
    const auto p0 = __builtin_amdgcn_cvt_pkrtz(a.x, a.y);
    const auto p1 = __builtin_amdgcn_cvt_pkrtz(a.z, a.w);
    const auto p2 = __builtin_amdgcn_cvt_pkrtz(b.x, b.y);
    const auto p3 = __builtin_amdgcn_cvt_pkrtz(b.z, b.w);
    uint4 u;
    u.x = __builtin_bit_cast(unsigned, p0);
    u.y = __builtin_bit_cast(unsigned, p1);
    u.z = __builtin_bit_cast(unsigned, p2);
    u.w = __builtin_bit_cast(unsigned, p3);
    return u;
}

// ---------------------------------------------------------------------------
// Kernel 1: k-split streaming scores + per-block top-16 per batch row.
// 8 waves (512 threads); wave w owns k-slice [64w, 64w+64). Its A-slice is
// a[2][4] = 32 VGPRs (built once from L2-hot brep) — small enough that the
// 128-VGPR cap from __launch_bounds__(512,4) can NEVER force a spill (R10's
// failure mode: 64-VGPR A array + 128 cap -> scratch spill, 17MB/dispatch).
// Per tile (64 rep rows): 8 flattened (nsub,ks2) steps, depth-1 y prefetch
// that also crosses the tile barrier; 4 MFMAs/step; partial dots + ynorm
// fold into int32 slds via ds_atomic (exact, deterministic, order-free).
// 2 barriers/tile; rotating wave scans top-16 and re-zeroes slds.
// Tiles assigned strided (t = b + s*NBLK) for balance + sequential sweep.
// ---------------------------------------------------------------------------
__global__ __launch_bounds__(512, 4) void dist_topk_kernel(
    const float* __restrict__ reps, const float* __restrict__ brep,
    float* __restrict__ cs, int* __restrict__ ci,
    int N, int TT, int NBLK)
{
    __shared__ int slds[64][65];                  // [rep-row][64 dots + ynorm]
    __shared__ int topdI[16][64];
    __shared__ int topiI[16][64];
    __shared__ int thrS[64], thrnS[64], cntS[64];

    const int tid = threadIdx.x;
    const int w = tid >> 6, lane = tid & 63;      // w = 0..7
    const int li = lane & 15, q = lane >> 4;
    const int b = blockIdx.x;
    const int kbase = 64 * w + 8 * q;

    // ---- A-fragments for this wave's k-slice, in registers (32 VGPR) ----
    // a[ks2][mt] = A[m = mt*16 + li][k = 64w + 32*ks2 + 8q + j], j=0..7
    uint4 a[2][4];
    #pragma unroll
    for (int ks2 = 0; ks2 < 2; ks2++)
        #pragma unroll
        for (int mt = 0; mt < 4; mt++) {
            const float* src = brep + (mt * 16 + li) * 512 + kbase + 32 * ks2;
            const float4 x0 = *(const float4*)(src);
            const float4 x1 = *(const float4*)(src + 4);
            a[ks2][mt] = pack8(x0, x1);
        }

    if (tid < 64) { thrS[tid] = INF_I; thrnS[tid] = INF_I; cntS[tid] = 0; }
    for (int i = tid; i < 64 * 65; i += 512) ((int*)slds)[i] = 0;
    __syncthreads();

    // prologue prefetch: tile b, step 0 (nsub 0, ks2 0)
    float4 yA0, yA1;
    {
        const int r0 = min(b * 64 + li, N - 1);
        const float* p = reps + (size_t)r0 * 512 + kbase;
        yA0 = *(const float4*)(p);
        yA1 = *(const float4*)(p + 4);
    }

    int sc = 0;
    for (int t = b; t < TT; t += NBLK, sc++) {
        const int n0 = t * 64;

        f32x4 acc0, acc1, acc2, acc3;
        float yn = 0.f;

        #pragma unroll
        for (int s = 0; s < 8; s++) {
            const int nsub = s >> 1, ks2 = s & 1;
            // ---- prefetch next step (crosses the tile barrier at s==7) ----
            float4 yB0, yB1;
            {
                int nt0, ns;
                if (s < 7) { nt0 = n0; ns = s + 1; }
                else       { nt0 = min(t + NBLK, TT - 1) * 64; ns = 0; }
                const int rr = min(nt0 + (ns >> 1) * 16 + li, N - 1);
                const float* p = reps + (size_t)rr * 512 + kbase + 32 * (ns & 1);
                yB0 = *(const float4*)(p);
                yB1 = *(const float4*)(p + 4);
            }
            if (ks2 == 0) {
                acc0 = (f32x4){0.f,0.f,0.f,0.f}; acc1 = (f32x4){0.f,0.f,0.f,0.f};
                acc2 = (f32x4){0.f,0.f,0.f,0.f}; acc3 = (f32x4){0.f,0.f,0.f,0.f};
                yn = 0.f;
            }
            yn = fmaf(yA0.x, yA0.x, fmaf(yA0.y, yA0.y, fmaf(yA0.z, yA0.z, fmaf(yA0.w, yA0.w, yn))));
            yn = fmaf(yA1.x, yA1.x, fmaf(yA1.y, yA1.y, fmaf(yA1.z, yA1.z, fmaf(yA1.w, yA1.w, yn))));
            const f16x8 bf = __builtin_bit_cast(f16x8, pack8(yA0, yA1));
            acc0 = __builtin_amdgcn_mfma_f32_16x16x32_f16(__builtin_bit_cast(f16x8, a[ks2][0]), bf, acc0, 0, 0, 0);
            acc1 = __builtin_amdgcn_mfma_f32_16x16x32_f16(__builtin_bit_cast(f16x8, a[ks2][1]), bf, acc1, 0, 0, 0);
            acc2 = __builtin_amdgcn_mfma_f32_16x16x32_f16(__builtin_bit_cast(f16x8, a[ks2][2]), bf, acc2, 0, 0, 0);
            acc3 = __builtin_amdgcn_mfma_f32_16x16x32_f16(__builtin_bit_cast(f16x8, a[ks2][3]), bf, acc3, 0, 0, 0);
            if (ks2 == 1) {
                // ---- fold this wave's k-slice partials into slds (exact int) ----
                float ys = yn;
                ys += __shfl_xor(ys, 16);
                ys += __shfl_xor(ys, 32);
                const int nloc = nsub * 16 + li;
                if (q == 0) atomicAdd(&slds[nloc][64], __float2int_rn(ys * SCALE));
                #pragma unroll
                for (int jj = 0; jj < 4; jj++) {
                    atomicAdd(&slds[nloc][ 0 + 4 * q + jj], __float2int_rn(acc0[jj] * SCALE));
                    atomicAdd(&slds[nloc][16 + 4 * q + jj], __float2int_rn(acc1[jj] * SCALE));
                    atomicAdd(&slds[nloc][32 + 4 * q + jj], __float2int_rn(acc2[jj] * SCALE));
                    atomicAdd(&slds[nloc][48 + 4 * q + jj], __float2int_rn(acc3[jj] * SCALE));
                }
            }
            yA0 = yB0; yA1 = yB1;
        }

        __syncthreads();   // all atomics of this tile done

        if (w == (sc & 7)) {
            const int r = lane;                   // batch row 0..63
            const int* sb = &slds[0][0];
            int thr = thrS[r], thrn = thrnS[r], cnt = cntS[r];
            for (int j = 0; j < 64; j++) {
                const int n = n0 + j;
                if (n >= N) break;
                const int s = sb[j * 65 + 64] - 2 * sb[j * 65 + r];
                if (lexLessI(s, n, thr, thrn)) {
                    if (cnt < 16) {
                        topdI[cnt][r] = s; topiI[cnt][r] = n; cnt++;
                        if (cnt == 16) {
                            int tv = topdI[0][r], tn = topiI[0][r];
                            #pragma unroll
                            for (int u = 1; u < 16; u++) {
                                int v = topdI[u][r], nn = topiI[u][r];
                                if (!lexLessI(v, nn, tv, tn)) { tv = v; tn = nn; }
                            }
                            thr = tv; thrn = tn;
                        }
                    } else {
                        #pragma unroll
                        for (int u = 0; u < 16; u++)
                            if (topdI[u][r] == thr && topiI[u][r] == thrn) {
                                topdI[u][r] = s; topiI[u][r] = n; break;
                            }
                        int tv = topdI[0][r], tn = topiI[0][r];
                        #pragma unroll
                        for (int u = 1; u < 16; u++) {
                            int v = topdI[u][r], nn = topiI[u][r];
                            if (!lexLessI(v, nn, tv, tn)) { tv = v; tn = nn; }
                        }
                        thr = tv; thrn = tn;
                    }
                }
            }
            thrS[r] = thr; thrnS[r] = thrn; cntS[r] = cnt;
            // zero slds for the next tile (scan wave owns this window)
            for (int e2 = lane; e2 < 64 * 65; e2 += 64) (&slds[0][0])[e2] = 0;
        }

        __syncthreads();   // slds zeroed before next tile's atomics
    }

    __syncthreads();
    if (tid < 64) {
        const int c = cntS[tid];
        const size_t base = ((size_t)b * 64 + tid) * 16;
        for (int j = 0; j < 16; j++) {
            cs[base + j] = (j < c) ? ((float)topdI[j][tid] * (1.0f / SCALE)) : INF_F;
            ci[base + j] = (j < c) ? topiI[j][tid] : INF_I;
        }
    }
}

// ---------------------------------------------------------------------------
// Kernel 2: per batch row — approx global top-24 merge (replace-max, the
// proven fast variant), fp64 exact recompute, exact sort -> top-16,
// softmax weights, action gather, outputs.
// ---------------------------------------------------------------------------
__global__ __launch_bounds__(256) void merge_kernel(
    const float* __restrict__ cs, const int* __restrict__ ci,
    const float* __restrict__ brep, const float* __restrict__ reps,
    const float* __restrict__ acts,
    float* __restrict__ out, int NLISTS, int N, int BA)
{
    const int r = blockIdx.x;
    const int tid = threadIdx.x;
    __shared__ __align__(16) float xrow[512];
    __shared__ float S1s[256 * KM];
    __shared__ int   S1i[256 * KM];
    __shared__ float S2s[32 * KM];
    __shared__ int   S2i[32 * KM];
    __shared__ double fd[KM];
    __shared__ int    fn[KM];

    if (tid < 128)
        *(float4*)(&xrow[tid * 4]) = *(const float4*)(&brep[(size_t)r * 512 + tid * 4]);

    float ls[KM]; int li[KM];
    #pragma unroll
    for (int j = 0; j < KM; j++) { ls[j] = INF_F; li[j] = INF_I; }
    float mv = INF_F; int mn = INF_I; int mp = 0;
    const int total = NLISTS * 16;
    for (int e = tid; e < total; e += 256) {
        const int blk = e >> 4, j = e & 15;
        const size_t a = (size_t)blk * 1024 + (size_t)r * 16 + j;
        const float s = cs[a]; const int n = ci[a];
        if (lexLess(s, n, mv, mn)) {
            ls[mp] = s; li[mp] = n;
            mv = ls[0]; mn = li[0]; mp = 0;
            #pragma unroll
            for (int u = 1; u < KM; u++)
                if (!lexLess(ls[u], li[u], mv, mn)) { mv = ls[u]; mn = li[u]; mp = u; }
        }
    }
    #pragma unroll
    for (int j = 0; j < KM; j++) { S1s[tid * KM + j] = ls[j]; S1i[tid * KM + j] = li[j]; }
    __syncthreads();

    if (tid < 32) {
        #pragma unroll
        for (int j = 0; j < KM; j++) { ls[j] = INF_F; li[j] = INF_I; }
        mv = INF_F; mn = INF_I; mp = 0;
        for (int e = tid * 8 * KM; e < (tid * 8 + 8) * KM; e++) {
            const float s = S1s[e]; const int n = S1i[e];
            if (lexLess(s, n, mv, mn)) {
                ls[mp] = s; li[mp] = n;
                mv = ls[0]; mn = li[0]; mp = 0;
                #pragma unroll
                for (int u = 1; u < KM; u++)
                    if (!lexLess(ls[u], li[u], mv, mn)) { mv = ls[u]; mn = li[u]; mp = u; }
            }
        }
        #pragma unroll
        for (int j = 0; j < KM; j++) { S2s[tid * KM + j] = ls[j]; S2i[tid * KM + j] = li[j]; }
    }
    __syncthreads();

    if (tid == 0) {
        #pragma unroll
        for (int j = 0; j < KM; j++) { ls[j] = INF_F; li[j] = INF_I; }
        mv = INF_F; mn = INF_I; mp = 0;
        for (int e = 0; e < 32 * KM; e++) {
            const float s = S2s[e]; const int n = S2i[e];
            if (lexLess(s, n, mv, mn)) {
                ls[mp] = s; li[mp] = n;
                mv = ls[0]; mn = li[0]; mp = 0;
                #pragma unroll
                for (int u = 1; u < KM; u++)
                    if (!lexLess(ls[u], li[u], mv, mn)) { mv = ls[u]; mn = li[u]; mp = u; }
            }
        }
        for (int j = 0; j < KM; j++) fn[j] = li[j];
    }
    __syncthreads();

    if (tid < KM) {
        const int n = fn[tid];
        double d = 1.0e300;
        if (n >= 0 && n < N) {
            d = 0.0;
            const float* yp = reps + (size_t)n * 512;
            for (int i = 0; i < 512; i += 4) {
                float4 yv = *(const float4*)(yp + i);
                double d0 = (double)xrow[i + 0] - (double)yv.x;
                double d1 = (double)xrow[i + 1] - (double)yv.y;
                double d2 = (double)xrow[i + 2] - (double)yv.z;
                double d3 = (double)xrow[i + 3] - (double)yv.w;
                d += d0 * d0 + d1 * d1 + d2 * d2 + d3 * d3;
            }
        }
        fd[tid] = d;
    }
    __syncthreads();

    if (tid == 0) {
        int ord[KM];
        for (int j = 0; j < KM; j++) ord[j] = j;
        for (int a = 0; a < 16; a++) {
            int best = a;
            for (int u = a + 1; u < KM; u++) {
                const int ou = ord[u], ob = ord[best];
                if (fd[ou] < fd[ob] || (fd[ou] == fd[ob] && fn[ou] < fn[ob])) best = u;
            }
            int tmp = ord[a]; ord[a] = ord[best]; ord[best] = tmp;
        }
        double dist[16];
        for (int j = 0; j < 16; j++) {
            double v = fd[ord[j]];
            dist[j] = sqrt(v > 0.0 ? v : 0.0);
        }
        double wv[16], wsum = 0.0;
        for (int j = 0; j < 16; j++) { wv[j] = exp(dist[0] - dist[j]); wsum += wv[j]; }
        for (int a = 0; a < 7; a++) {
            double s = 0.0;
            for (int j = 0; j < 16; j++)
                s += wv[j] * (double)acts[(size_t)fn[ord[j]] * 7 + a];
            out[r * 7 + a] = (float)(s / wsum);
        }
        for (int j = 0; j < 16; j++)
            out[BA + r * 16 + j] = (float)fn[ord[j]];
    }
}

extern "C" void kernel_launch(void* const* d_in, const int* in_sizes, int n_in,
                              void* d_out, int out_size, void* d_ws, size_t ws_size,
                              hipStream_t stream) {
    const float* brep = (const float*)d_in[0];
    const float* reps = (const float*)d_in[1];
    const float* acts = (const float*)d_in[2];
    const int D = 512;
    const int B = in_sizes[0] / D;   // 64
    const int N = in_sizes[1] / D;   // 500000
    float* out = (float*)d_out;

    // 512 blocks of 512 threads = 2 blocks/CU (16 waves/CU, 25.6KB LDS).
    int NBLK = 512;
    const size_t perblk = (size_t)64 * 16 * 8;        // cs+ci bytes per block
    while (NBLK > 1 && (size_t)NBLK * perblk > ws_size) NBLK >>= 1;

    float* cs = (float*)d_ws;
    int* ci = (int*)((char*)d_ws + (size_t)NBLK * 64 * 16 * 4);

    const int TT = (N + 63) / 64;                     // 64-row tiles

    dist_topk_kernel<<<NBLK, 512, 0, stream>>>(reps, brep, cs, ci, N, TT, NBLK);
    merge_kernel<<<B, 256, 0, stream>>>(cs, ci, brep, reps, acts, out, NBLK, N, B * 7);
}